// Round 10
// baseline (182.832 us; speedup 1.0000x reference)
//
#include <hip/hip_runtime.h>

#define GRP   8
#define FO    256
#define CIN   512
#define PTILE 32
#define XROW  520          // u16 per staged x row (512 + 8 pad)
#define NT32  784          // 25088 / 32

typedef __attribute__((ext_vector_type(8))) short bf16x8;
typedef __attribute__((ext_vector_type(4))) float f32x4;

__device__ __forceinline__ unsigned f2bu(float f) {
    unsigned u = __float_as_uint(f);
    return (u + 0x7FFFu + ((u >> 16) & 1u)) >> 16;   // RNE to bf16 (validated R1)
}
__device__ __forceinline__ short f2b(float f) { return (short)f2bu(f); }
__device__ __forceinline__ unsigned pk2(float a, float b) {
    return f2bu(a) | (f2bu(b) << 16);
}
__device__ __forceinline__ float ulo(unsigned u) { return __uint_as_float(u << 16); }
__device__ __forceinline__ float uhi(unsigned u) { return __uint_as_float(u & 0xffff0000u); }
__device__ __forceinline__ float sigmoidf_(float b) {
    return 1.0f / (1.0f + __expf(-b));
}

// ---- pre-kernel: repack kernels fp32 [g][p][f] -> bf16 MFMA A-frag order ----
// wpk[(((g*16+t)*2+kb)*64+lane)*8+j] = w[g][ p=kb*32+(lane>>4)*8+j ][ f=t*16+(lane&15) ]
__global__ void repack_w(const float* __restrict__ wk, unsigned short* __restrict__ wpk) {
    int id = blockIdx.x * 256 + threadIdx.x;      // 0 .. 131071
    int j    = id & 7;
    int lane = (id >> 3) & 63;
    int kb   = (id >> 9) & 1;
    int t    = (id >> 10) & 15;
    int g    = id >> 14;
    int p = kb * 32 + (lane >> 4) * 8 + j;
    int f = t * 16 + (lane & 15);
    wpk[id] = (unsigned short)f2bu(wk[(g * 64 + p) * FO + f]);
}

__global__ __launch_bounds__(512, 4)
void dynroute_pk32(const float* __restrict__ x, const unsigned short* __restrict__ wpk,
                   const float* __restrict__ bias, float* __restrict__ out) {
    __shared__ unsigned short xs[PTILE * XROW];   // 33.3 KB bf16 x tile
    __shared__ float part_s[8][PTILE][8];         // [wave][pos][g], 8 KB
    __shared__ float alpha1_s[PTILE][8];
    __shared__ float alpha2_s[PTILE][8];

    const int tid  = threadIdx.x;
    const int lane = tid & 63;
    const int wave = tid >> 6;                // 0..7, owns f-tiles wave*2 + {0,1}
    const int pos  = lane & 15;
    const int lq   = lane >> 4;               // 0..3
    const long m0  = (long)blockIdx.x * PTILE;

    // ---------------- stage x tile -> LDS as bf16 --------------------------
    {
        const int row = tid >> 4;             // 0..31 (16 threads per row)
        const int c0  = (tid & 15) * 32;      // f32 col, 32 per thread
        const float* p = x + (m0 + row) * CIN + c0;
        #pragma unroll
        for (int k = 0; k < 4; ++k) {
            const float4 u0 = *reinterpret_cast<const float4*>(p + k * 8);
            const float4 u1 = *reinterpret_cast<const float4*>(p + k * 8 + 4);
            bf16x8 v;
            v[0] = f2b(u0.x); v[1] = f2b(u0.y); v[2] = f2b(u0.z); v[3] = f2b(u0.w);
            v[4] = f2b(u1.x); v[5] = f2b(u1.y); v[6] = f2b(u1.z); v[7] = f2b(u1.w);
            *reinterpret_cast<bf16x8*>(&xs[row * XROW + c0 + k * 8]) = v;
        }
    }
    __syncthreads();

    // ---------------- MFMA: con (bf16-packed) for 2 pos-tiles --------------
    // cl/ch[pt][tt][g]: lane holds f = (wave*2+tt)*16 + lq*4 + {0..3},
    // position = pt*16 + pos
    unsigned cl[2][2][GRP], ch[2][2][GRP];
    {
        const unsigned short* wb = wpk + wave * 2048 + lane * 8;
        #pragma unroll
        for (int g = 0; g < GRP; ++g) {
            const bf16x8 wf00 = *reinterpret_cast<const bf16x8*>(wb + g * 16384);
            const bf16x8 wf01 = *reinterpret_cast<const bf16x8*>(wb + g * 16384 + 512);
            const bf16x8 wf10 = *reinterpret_cast<const bf16x8*>(wb + g * 16384 + 1024);
            const bf16x8 wf11 = *reinterpret_cast<const bf16x8*>(wb + g * 16384 + 1536);
            #pragma unroll
            for (int pt = 0; pt < 2; ++pt) {
                const unsigned short* xr = &xs[(pt * 16 + pos) * XROW + g * 64 + lq * 8];
                const bf16x8 xf0 = *reinterpret_cast<const bf16x8*>(xr);
                const bf16x8 xf1 = *reinterpret_cast<const bf16x8*>(xr + 32);
                f32x4 a0 = {0.f, 0.f, 0.f, 0.f};
                a0 = __builtin_amdgcn_mfma_f32_16x16x32_bf16(wf00, xf0, a0, 0, 0, 0);
                a0 = __builtin_amdgcn_mfma_f32_16x16x32_bf16(wf01, xf1, a0, 0, 0, 0);
                cl[pt][0][g] = pk2(a0[0], a0[1]);
                ch[pt][0][g] = pk2(a0[2], a0[3]);
                f32x4 a1 = {0.f, 0.f, 0.f, 0.f};
                a1 = __builtin_amdgcn_mfma_f32_16x16x32_bf16(wf10, xf0, a1, 0, 0, 0);
                a1 = __builtin_amdgcn_mfma_f32_16x16x32_bf16(wf11, xf1, a1, 0, 0, 0);
                cl[pt][1][g] = pk2(a1[0], a1[1]);
                ch[pt][1][g] = pk2(a1[2], a1[3]);
            }
        }
    }

    // ---------------- routing round 1: d1[g] = <con_g, S> ------------------
    float d1[2][GRP];
    #pragma unroll
    for (int pt = 0; pt < 2; ++pt) {
        f32x4 S0 = {0.f, 0.f, 0.f, 0.f}, S1 = {0.f, 0.f, 0.f, 0.f};
        #pragma unroll
        for (int g = 0; g < GRP; ++g) {
            S0[0] += ulo(cl[pt][0][g]); S0[1] += uhi(cl[pt][0][g]);
            S0[2] += ulo(ch[pt][0][g]); S0[3] += uhi(ch[pt][0][g]);
            S1[0] += ulo(cl[pt][1][g]); S1[1] += uhi(cl[pt][1][g]);
            S1[2] += ulo(ch[pt][1][g]); S1[3] += uhi(ch[pt][1][g]);
        }
        #pragma unroll
        for (int g = 0; g < GRP; ++g) {
            float s =      ulo(cl[pt][0][g]) * S0[0];
            s = fmaf(uhi(cl[pt][0][g]), S0[1], s);
            s = fmaf(ulo(ch[pt][0][g]), S0[2], s);
            s = fmaf(uhi(ch[pt][0][g]), S0[3], s);
            s = fmaf(ulo(cl[pt][1][g]), S1[0], s);
            s = fmaf(uhi(cl[pt][1][g]), S1[1], s);
            s = fmaf(ulo(ch[pt][1][g]), S1[2], s);
            s = fmaf(uhi(ch[pt][1][g]), S1[3], s);
            d1[pt][g] = s;
        }
    }
    #pragma unroll
    for (int pt = 0; pt < 2; ++pt)
        #pragma unroll
        for (int g = 0; g < GRP; ++g) {
            d1[pt][g] += __shfl_xor(d1[pt][g], 16, 64);
            d1[pt][g] += __shfl_xor(d1[pt][g], 32, 64);
        }
    if (lq == 0) {
        #pragma unroll
        for (int pt = 0; pt < 2; ++pt) {
            float4 v0 = {d1[pt][0], d1[pt][1], d1[pt][2], d1[pt][3]};
            float4 v1 = {d1[pt][4], d1[pt][5], d1[pt][6], d1[pt][7]};
            *reinterpret_cast<float4*>(&part_s[wave][pt * 16 + pos][0]) = v0;
            *reinterpret_cast<float4*>(&part_s[wave][pt * 16 + pos][4]) = v1;
        }
    }
    __syncthreads();   // B1

    float b1r = 0.f;
    if (tid < 256) {       // thread handles (pos = tid>>3, g = tid&7)
        const int rp = tid >> 3, rg = tid & 7;
        float s = 0.f;
        #pragma unroll
        for (int w = 0; w < 8; ++w) s += part_s[w][rp][rg];
        b1r = 0.5f * s;
        alpha1_s[rp][rg] = sigmoidf_(b1r);
    }
    __syncthreads();   // B2

    // ---------------- routing round 2: d2[g] = <con_g, S_alpha> ------------
    float d2[2][GRP];
    #pragma unroll
    for (int pt = 0; pt < 2; ++pt) {
        f32x4 sa0 = {0.f, 0.f, 0.f, 0.f}, sa1 = {0.f, 0.f, 0.f, 0.f};
        #pragma unroll
        for (int g = 0; g < GRP; ++g) {
            const float a = alpha1_s[pt * 16 + pos][g];
            sa0[0] = fmaf(a, ulo(cl[pt][0][g]), sa0[0]);
            sa0[1] = fmaf(a, uhi(cl[pt][0][g]), sa0[1]);
            sa0[2] = fmaf(a, ulo(ch[pt][0][g]), sa0[2]);
            sa0[3] = fmaf(a, uhi(ch[pt][0][g]), sa0[3]);
            sa1[0] = fmaf(a, ulo(cl[pt][1][g]), sa1[0]);
            sa1[1] = fmaf(a, uhi(cl[pt][1][g]), sa1[1]);
            sa1[2] = fmaf(a, ulo(ch[pt][1][g]), sa1[2]);
            sa1[3] = fmaf(a, uhi(ch[pt][1][g]), sa1[3]);
        }
        #pragma unroll
        for (int g = 0; g < GRP; ++g) {
            float s =      ulo(cl[pt][0][g]) * sa0[0];
            s = fmaf(uhi(cl[pt][0][g]), sa0[1], s);
            s = fmaf(ulo(ch[pt][0][g]), sa0[2], s);
            s = fmaf(uhi(ch[pt][0][g]), sa0[3], s);
            s = fmaf(ulo(cl[pt][1][g]), sa1[0], s);
            s = fmaf(uhi(cl[pt][1][g]), sa1[1], s);
            s = fmaf(ulo(ch[pt][1][g]), sa1[2], s);
            s = fmaf(uhi(ch[pt][1][g]), sa1[3], s);
            d2[pt][g] = s;
        }
    }
    #pragma unroll
    for (int pt = 0; pt < 2; ++pt)
        #pragma unroll
        for (int g = 0; g < GRP; ++g) {
            d2[pt][g] += __shfl_xor(d2[pt][g], 16, 64);
            d2[pt][g] += __shfl_xor(d2[pt][g], 32, 64);
        }
    if (lq == 0) {
        #pragma unroll
        for (int pt = 0; pt < 2; ++pt) {
            float4 v0 = {d2[pt][0], d2[pt][1], d2[pt][2], d2[pt][3]};
            float4 v1 = {d2[pt][4], d2[pt][5], d2[pt][6], d2[pt][7]};
            *reinterpret_cast<float4*>(&part_s[wave][pt * 16 + pos][0]) = v0;
            *reinterpret_cast<float4*>(&part_s[wave][pt * 16 + pos][4]) = v1;
        }
    }
    __syncthreads();   // B3

    if (tid < 256) {
        const int rp = tid >> 3, rg = tid & 7;
        float s = 0.f;
        #pragma unroll
        for (int w = 0; w < 8; ++w) s += part_s[w][rp][rg];
        alpha2_s[rp][rg] = sigmoidf_(b1r + s);
    }
    __syncthreads();   // B4

    // ---------------- epilogue: out = sum_g alpha2[g]*con_g + bias ---------
    const float4 bb0 = *reinterpret_cast<const float4*>(bias + (wave * 2 + 0) * 16 + lq * 4);
    const float4 bb1 = *reinterpret_cast<const float4*>(bias + (wave * 2 + 1) * 16 + lq * 4);
    #pragma unroll
    for (int pt = 0; pt < 2; ++pt) {
        f32x4 o0 = {bb0.x, bb0.y, bb0.z, bb0.w};
        f32x4 o1 = {bb1.x, bb1.y, bb1.z, bb1.w};
        #pragma unroll
        for (int g = 0; g < GRP; ++g) {
            const float a = alpha2_s[pt * 16 + pos][g];
            o0[0] = fmaf(a, ulo(cl[pt][0][g]), o0[0]);
            o0[1] = fmaf(a, uhi(cl[pt][0][g]), o0[1]);
            o0[2] = fmaf(a, ulo(ch[pt][0][g]), o0[2]);
            o0[3] = fmaf(a, uhi(ch[pt][0][g]), o0[3]);
            o1[0] = fmaf(a, ulo(cl[pt][1][g]), o1[0]);
            o1[1] = fmaf(a, uhi(cl[pt][1][g]), o1[1]);
            o1[2] = fmaf(a, ulo(ch[pt][1][g]), o1[2]);
            o1[3] = fmaf(a, uhi(ch[pt][1][g]), o1[3]);
        }
        float* ob = out + (m0 + pt * 16 + pos) * FO + lq * 4;
        *reinterpret_cast<float4*>(ob + (wave * 2 + 0) * 16) = *reinterpret_cast<float4*>(&o0);
        *reinterpret_cast<float4*>(ob + (wave * 2 + 1) * 16) = *reinterpret_cast<float4*>(&o1);
    }
}

extern "C" void kernel_launch(void* const* d_in, const int* in_sizes, int n_in,
                              void* d_out, int out_size, void* d_ws, size_t ws_size,
                              hipStream_t stream) {
    const float* x    = (const float*)d_in[0];
    const float* wk   = (const float*)d_in[1];
    const float* bias = (const float*)d_in[2];
    float* out        = (float*)d_out;
    unsigned short* wpk = (unsigned short*)d_ws;   // 256 KB of workspace

    hipLaunchKernelGGL(repack_w, dim3(512), dim3(256), 0, stream, wk, wpk);
    hipLaunchKernelGGL(dynroute_pk32, dim3(NT32), dim3(512), 0, stream,
                       x, wpk, bias, out);
}

// Round 11
// 91.781 us; speedup vs baseline: 1.9920x; 1.9920x over previous
//
#include <hip/hip_runtime.h>

#define GRP   8
#define FO    256
#define CIN   512
#define PTILE 32
#define XROW  520          // u16 per staged x row (512 + 8 pad)
#define NT32  784          // 25088 / 32

typedef __attribute__((ext_vector_type(8))) short bf16x8;
typedef __attribute__((ext_vector_type(4))) float f32x4;

__device__ __forceinline__ unsigned f2bu(float f) {
    unsigned u = __float_as_uint(f);
    return (u + 0x7FFFu + ((u >> 16) & 1u)) >> 16;   // RNE to bf16 (validated R1)
}
__device__ __forceinline__ short f2b(float f) { return (short)f2bu(f); }
__device__ __forceinline__ float sigmoidf_(float b) {
    return 1.0f / (1.0f + __expf(-b));
}
__device__ __forceinline__ float dot4(f32x4 a, f32x4 b) {
    return fmaf(a[0], b[0], fmaf(a[1], b[1], fmaf(a[2], b[2], a[3] * b[3])));
}

// ---- pre-kernel: repack kernels fp32 [g][p][f] -> bf16 MFMA A-frag order ----
// wpk[(((g*16+t)*2+kb)*64+lane)*8+j] = w[g][ p=kb*32+(lane>>4)*8+j ][ f=t*16+(lane&15) ]
__global__ void repack_w(const float* __restrict__ wk, unsigned short* __restrict__ wpk) {
    int id = blockIdx.x * 256 + threadIdx.x;      // 0 .. 131071
    int j    = id & 7;
    int lane = (id >> 3) & 63;
    int kb   = (id >> 9) & 1;
    int t    = (id >> 10) & 15;
    int g    = id >> 14;
    int p = kb * 32 + (lane >> 4) * 8 + j;
    int f = t * 16 + (lane & 15);
    wpk[id] = (unsigned short)f2bu(wk[(g * 64 + p) * FO + f]);
}

__global__ __launch_bounds__(1024, 1)
void dynroute_32(const float* __restrict__ x, const unsigned short* __restrict__ wpk,
                 const float* __restrict__ bias, float* __restrict__ out) {
    __shared__ unsigned short xs[PTILE * XROW];   // 33.3 KB bf16 x tile
    __shared__ float part_s[16][PTILE][8];        // [wave][pos][g], 16 KB
    __shared__ float alpha1_s[PTILE][8];
    __shared__ float alpha2_s[PTILE][8];

    const int tid  = threadIdx.x;
    const int lane = tid & 63;
    const int wave = tid >> 6;                // 0..15 == f-tile t
    const int pos  = lane & 15;
    const int lq   = lane >> 4;               // 0..3
    const long m0  = (long)blockIdx.x * PTILE;

    // ---------------- stage x tile -> LDS as bf16 --------------------------
    {
        const int row = tid >> 5;             // 0..31 (32 threads per row)
        const int c0  = (tid & 31) * 16;      // f32 col, 16 per thread
        const float* p = x + (m0 + row) * CIN + c0;
        #pragma unroll
        for (int k = 0; k < 2; ++k) {
            const float4 u0 = *reinterpret_cast<const float4*>(p + k * 8);
            const float4 u1 = *reinterpret_cast<const float4*>(p + k * 8 + 4);
            bf16x8 v;
            v[0] = f2b(u0.x); v[1] = f2b(u0.y); v[2] = f2b(u0.z); v[3] = f2b(u0.w);
            v[4] = f2b(u1.x); v[5] = f2b(u1.y); v[6] = f2b(u1.z); v[7] = f2b(u1.w);
            *reinterpret_cast<bf16x8*>(&xs[row * XROW + c0 + k * 8]) = v;
        }
    }
    __syncthreads();

    // ---------------- MFMA: con for 2 pos-tiles, f32 in AGPRs --------------
    // acc[pt][g]: lane holds con[pt*16+pos][f = wave*16 + lq*4 + r]
    f32x4 acc[2][GRP];
    {
        const unsigned short* wb = wpk + wave * 1024 + lane * 8;
        #pragma unroll
        for (int g = 0; g < GRP; ++g) {
            const bf16x8 wf0 = *reinterpret_cast<const bf16x8*>(wb + g * 16384);
            const bf16x8 wf1 = *reinterpret_cast<const bf16x8*>(wb + g * 16384 + 512);
            #pragma unroll
            for (int pt = 0; pt < 2; ++pt) {
                const unsigned short* xr = &xs[(pt * 16 + pos) * XROW + g * 64 + lq * 8];
                const bf16x8 xf0 = *reinterpret_cast<const bf16x8*>(xr);
                const bf16x8 xf1 = *reinterpret_cast<const bf16x8*>(xr + 32);
                f32x4 a = {0.f, 0.f, 0.f, 0.f};
                a = __builtin_amdgcn_mfma_f32_16x16x32_bf16(wf0, xf0, a, 0, 0, 0);
                a = __builtin_amdgcn_mfma_f32_16x16x32_bf16(wf1, xf1, a, 0, 0, 0);
                acc[pt][g] = a;
            }
        }
    }

    // ---------------- routing round 1: d1[g] = <con_g, S>, per pt ----------
    #pragma unroll
    for (int pt = 0; pt < 2; ++pt) {
        f32x4 S = acc[pt][0];
        #pragma unroll
        for (int g = 1; g < GRP; ++g) S += acc[pt][g];
        float d1[GRP];
        #pragma unroll
        for (int g = 0; g < GRP; ++g) d1[g] = dot4(acc[pt][g], S);
        #pragma unroll
        for (int g = 0; g < GRP; ++g) {
            d1[g] += __shfl_xor(d1[g], 16, 64);
            d1[g] += __shfl_xor(d1[g], 32, 64);
        }
        if (lq == 0) {
            float4 v0 = {d1[0], d1[1], d1[2], d1[3]};
            float4 v1 = {d1[4], d1[5], d1[6], d1[7]};
            *reinterpret_cast<float4*>(&part_s[wave][pt * 16 + pos][0]) = v0;
            *reinterpret_cast<float4*>(&part_s[wave][pt * 16 + pos][4]) = v1;
        }
    }
    __syncthreads();   // B1

    float b1r = 0.f;
    if (tid < 256) {       // thread handles (pos = tid>>3, g = tid&7)
        const int rp = tid >> 3, rg = tid & 7;
        float s = 0.f;
        #pragma unroll
        for (int w = 0; w < 16; ++w) s += part_s[w][rp][rg];
        b1r = 0.5f * s;
        alpha1_s[rp][rg] = sigmoidf_(b1r);
    }
    __syncthreads();   // B2

    // ---------------- routing round 2: d2[g] = <con_g, S_alpha>, per pt ----
    #pragma unroll
    for (int pt = 0; pt < 2; ++pt) {
        f32x4 sa = {0.f, 0.f, 0.f, 0.f};
        #pragma unroll
        for (int g = 0; g < GRP; ++g)
            sa = alpha1_s[pt * 16 + pos][g] * acc[pt][g] + sa;
        float d2[GRP];
        #pragma unroll
        for (int g = 0; g < GRP; ++g) d2[g] = dot4(acc[pt][g], sa);
        #pragma unroll
        for (int g = 0; g < GRP; ++g) {
            d2[g] += __shfl_xor(d2[g], 16, 64);
            d2[g] += __shfl_xor(d2[g], 32, 64);
        }
        if (lq == 0) {
            float4 v0 = {d2[0], d2[1], d2[2], d2[3]};
            float4 v1 = {d2[4], d2[5], d2[6], d2[7]};
            *reinterpret_cast<float4*>(&part_s[wave][pt * 16 + pos][0]) = v0;
            *reinterpret_cast<float4*>(&part_s[wave][pt * 16 + pos][4]) = v1;
        }
    }
    __syncthreads();   // B3

    if (tid < 256) {
        const int rp = tid >> 3, rg = tid & 7;
        float s = 0.f;
        #pragma unroll
        for (int w = 0; w < 16; ++w) s += part_s[w][rp][rg];
        alpha2_s[rp][rg] = sigmoidf_(b1r + s);
    }
    __syncthreads();   // B4

    // ---------------- epilogue: out = sum_g alpha2[g]*con_g + bias ---------
    const float4 bb = *reinterpret_cast<const float4*>(bias + wave * 16 + lq * 4);
    #pragma unroll
    for (int pt = 0; pt < 2; ++pt) {
        f32x4 o = {bb.x, bb.y, bb.z, bb.w};
        #pragma unroll
        for (int g = 0; g < GRP; ++g)
            o = alpha2_s[pt * 16 + pos][g] * acc[pt][g] + o;
        *reinterpret_cast<float4*>(
            out + (m0 + pt * 16 + pos) * FO + wave * 16 + lq * 4) =
            *reinterpret_cast<float4*>(&o);
    }
}

extern "C" void kernel_launch(void* const* d_in, const int* in_sizes, int n_in,
                              void* d_out, int out_size, void* d_ws, size_t ws_size,
                              hipStream_t stream) {
    const float* x    = (const float*)d_in[0];
    const float* wk   = (const float*)d_in[1];
    const float* bias = (const float*)d_in[2];
    float* out        = (float*)d_out;
    unsigned short* wpk = (unsigned short*)d_ws;   // 256 KB of workspace

    hipLaunchKernelGGL(repack_w, dim3(512), dim3(256), 0, stream, wk, wpk);
    hipLaunchKernelGGL(dynroute_32, dim3(NT32), dim3(1024), 0, stream,
                       x, wpk, bias, out);
}

// Round 12
// 68.460 us; speedup vs baseline: 2.6706x; 1.3407x over previous
//
#include <hip/hip_runtime.h>

#define GRP   8
#define FO    256
#define CIN   512
#define PTILE 16
#define XROW  520          // u16 per staged x row (512 + 8 pad)
#define NTILE 1568         // 25088 / 16

typedef __attribute__((ext_vector_type(8))) short bf16x8;
typedef __attribute__((ext_vector_type(4))) float f32x4;

__device__ __forceinline__ unsigned f2bu(float f) {
    unsigned u = __float_as_uint(f);
    return (u + 0x7FFFu + ((u >> 16) & 1u)) >> 16;   // RNE to bf16 (validated R1)
}
__device__ __forceinline__ short f2b(float f) { return (short)f2bu(f); }
__device__ __forceinline__ float sigmoidf_(float b) {
    return 1.0f / (1.0f + __expf(-b));
}
__device__ __forceinline__ float dot4(f32x4 a, f32x4 b) {
    return fmaf(a[0], b[0], fmaf(a[1], b[1], fmaf(a[2], b[2], a[3] * b[3])));
}

// ---- pre-kernel: repack kernels fp32 [g][p][f] -> bf16 MFMA A-frag order ----
// wpk[(((g*16+t)*2+kb)*64+lane)*8+j] = w[g][ p=kb*32+(lane>>4)*8+j ][ f=t*16+(lane&15) ]
__global__ void repack_w(const float* __restrict__ wk, unsigned short* __restrict__ wpk) {
    int id = blockIdx.x * 256 + threadIdx.x;      // 0 .. 131071
    int j    = id & 7;
    int lane = (id >> 3) & 63;
    int kb   = (id >> 9) & 1;
    int t    = (id >> 10) & 15;
    int g    = id >> 14;
    int p = kb * 32 + (lane >> 4) * 8 + j;
    int f = t * 16 + (lane & 15);
    wpk[id] = (unsigned short)f2bu(wk[(g * 64 + p) * FO + f]);
}

__global__ __launch_bounds__(1024, 1)
void dynroute_wq(const float* __restrict__ x, const unsigned short* __restrict__ wpk,
                 const float* __restrict__ bias, float* __restrict__ out) {
    __shared__ unsigned short xs[PTILE * XROW];     // 16.25 KB bf16 x tile
    __shared__ float con_s[PTILE * GRP * FO];       // 128 KB f32 con

    const int tid  = threadIdx.x;
    const int lane = tid & 63;
    const int wave = tid >> 6;                // 0..15 == f-tile t; also routing pos
    const int pos  = lane & 15;
    const int lq   = lane >> 4;               // 0..3
    const long m0  = (long)blockIdx.x * PTILE;

    // ---------------- stage x tile -> LDS as bf16 (wave w stages row w) ----
    {
        const float* p = x + (m0 + wave) * CIN + lane * 8;
        const float4 u0 = *reinterpret_cast<const float4*>(p);
        const float4 u1 = *reinterpret_cast<const float4*>(p + 4);
        bf16x8 v;
        v[0] = f2b(u0.x); v[1] = f2b(u0.y); v[2] = f2b(u0.z); v[3] = f2b(u0.w);
        v[4] = f2b(u1.x); v[5] = f2b(u1.y); v[6] = f2b(u1.z); v[7] = f2b(u1.w);
        *reinterpret_cast<bf16x8*>(&xs[wave * XROW + lane * 8]) = v;
    }
    __syncthreads();   // B0

    // ---------------- MFMA: con[pos][f=wave*16+lq*4+r] for all 8 g ---------
    f32x4 acc[GRP];
    {
        const unsigned short* wb = wpk + wave * 1024 + lane * 8;
        const unsigned short* xrow = &xs[pos * XROW];
        #pragma unroll
        for (int g = 0; g < GRP; ++g) {
            const bf16x8 wf0 = *reinterpret_cast<const bf16x8*>(wb + g * 16384);
            const bf16x8 wf1 = *reinterpret_cast<const bf16x8*>(wb + g * 16384 + 512);
            const bf16x8 xf0 = *reinterpret_cast<const bf16x8*>(&xrow[g * 64 + lq * 8]);
            const bf16x8 xf1 = *reinterpret_cast<const bf16x8*>(&xrow[g * 64 + 32 + lq * 8]);
            f32x4 a = {0.f, 0.f, 0.f, 0.f};
            a = __builtin_amdgcn_mfma_f32_16x16x32_bf16(wf0, xf0, a, 0, 0, 0);
            a = __builtin_amdgcn_mfma_f32_16x16x32_bf16(wf1, xf1, a, 0, 0, 0);
            acc[g] = a;
        }
    }

    // ---------------- write con -> LDS (swizzled rows, 2-way = free) -------
    {
        const int fsw = (wave * 16 + lq * 4) ^ ((pos & 7) << 2);   // f32-idx xor
        #pragma unroll
        for (int g = 0; g < GRP; ++g)
            *reinterpret_cast<f32x4*>(&con_s[(pos * GRP + g) * FO + fsw]) = acc[g];
    }
    __syncthreads();   // B1

    // ---------------- routing: wave w owns position w, all in-wave ---------
    f32x4 c[GRP];
    {
        const int rsw = (wave & 7) << 2;
        #pragma unroll
        for (int g = 0; g < GRP; ++g)
            c[g] = *reinterpret_cast<const f32x4*>(
                &con_s[(wave * GRP + g) * FO + ((lane * 4) ^ rsw)]);
    }

    // d1[g] = <con_g, S> over all 256 f (full-wave butterfly)
    f32x4 S = c[0];
    #pragma unroll
    for (int g = 1; g < GRP; ++g) S += c[g];
    float d1[GRP];
    #pragma unroll
    for (int g = 0; g < GRP; ++g) d1[g] = dot4(c[g], S);
    #pragma unroll
    for (int g = 0; g < GRP; ++g) {
        #pragma unroll
        for (int m = 1; m <= 32; m <<= 1) d1[g] += __shfl_xor(d1[g], m, 64);
    }
    float b1[GRP], a1[GRP];
    #pragma unroll
    for (int g = 0; g < GRP; ++g) {
        b1[g] = 0.5f * d1[g];
        a1[g] = sigmoidf_(b1[g]);
    }

    // d2[g] = <con_g, S_alpha>
    f32x4 sa = a1[0] * c[0];
    #pragma unroll
    for (int g = 1; g < GRP; ++g) sa = a1[g] * c[g] + sa;
    float d2[GRP];
    #pragma unroll
    for (int g = 0; g < GRP; ++g) d2[g] = dot4(c[g], sa);
    #pragma unroll
    for (int g = 0; g < GRP; ++g) {
        #pragma unroll
        for (int m = 1; m <= 32; m <<= 1) d2[g] += __shfl_xor(d2[g], m, 64);
    }

    // ---------------- epilogue: out = sum_g alpha2[g]*con_g + bias ---------
    const float4 bbv = *reinterpret_cast<const float4*>(bias + lane * 4);
    f32x4 o = {bbv.x, bbv.y, bbv.z, bbv.w};
    #pragma unroll
    for (int g = 0; g < GRP; ++g) {
        const float a2 = sigmoidf_(b1[g] + d2[g]);
        o = a2 * c[g] + o;
    }
    *reinterpret_cast<float4*>(out + (m0 + wave) * FO + lane * 4) =
        *reinterpret_cast<float4*>(&o);
}

extern "C" void kernel_launch(void* const* d_in, const int* in_sizes, int n_in,
                              void* d_out, int out_size, void* d_ws, size_t ws_size,
                              hipStream_t stream) {
    const float* x    = (const float*)d_in[0];
    const float* wk   = (const float*)d_in[1];
    const float* bias = (const float*)d_in[2];
    float* out        = (float*)d_out;
    unsigned short* wpk = (unsigned short*)d_ws;   // 256 KB of workspace

    hipLaunchKernelGGL(repack_w, dim3(512), dim3(256), 0, stream, wk, wpk);
    hipLaunchKernelGGL(dynroute_wq, dim3(NTILE), dim3(1024), 0, stream,
                       x, wpk, bias, out);
}